// Round 18
// baseline (250.870 us; speedup 1.0000x reference)
//
#include <hip/hip_runtime.h>

typedef _Float16 f16;
typedef _Float16 f16x8 __attribute__((ext_vector_type(8)));
typedef _Float16 f16x4 __attribute__((ext_vector_type(4)));
typedef float    f32x4 __attribute__((ext_vector_type(4)));

#define NN 16384   // 128*128

// ---- Chebyshev deg-11 approx of log(x) on x in [0.3, 3.5] (verified r11) ---
#define CHM 1.9f
#define CHH 1.6f
__device__ __constant__ float CB[12] = {
   0.6419309f,  0.8414791f, -0.3609340f,  0.2147234f,   // g0: b0..b3
  -0.0582120f, -0.0285232f, -0.3102016f,  0.3787296f,   // g1: b4..b7
   0.3577728f, -0.4226304f, -0.2457600f,  0.2444390f }; // g2: b8..b11
// Folded combos for H-substitution (U3 = (H - b8 I - b9 U - b10 U2)/b11):
//  g0' = e0 I + e1 U + e2 U2 + e3 H ;  g1' = c0 I + c1 U + c2 U2 + c3 H.
// Hand-verified at t=0 and t=1 vs original polynomial (residual <= 7e-7).
__device__ __constant__ float CF[8] = {
   0.3276514f,  1.2127320f, -0.1450500f,  0.8784340f,   // e0..e3 (final)
  -0.6125382f,  0.6262931f,  0.0705748f,  1.5493830f }; // c0..c3 (stored Horner)

// ---------------- swizzled LDS index for 128x128 f16 (G4 XOR pattern) -------
__device__ __forceinline__ int swz(int r, int c) {
  return (r << 7) + ((((c >> 3) ^ (r & 7)) << 3) | (c & 7));
}

// load 128x128 f16 (global, row-major) -> swizzled LDS (kD only)
__device__ __forceinline__ void load_g2l_h(const f16* __restrict__ G, f16* buf, int t, int nt) {
  for (int ch = t; ch < 2048; ch += nt) {
    int r = ch >> 4, c8 = (ch & 15) << 3;
    *(f16x8*)(buf + swz(r, c8)) = *(const f16x8*)(G + (r << 7) + c8);
  }
}

// async stage of a PRE-SWIZZLED 32KB f16 matrix -> LDS (linear copy).
__device__ __forceinline__ void stage32_512(const f16* __restrict__ src, f16* dst, int t) {
  const int w = t >> 6, l = t & 63;
  #pragma unroll
  for (int q = 0; q < 4; ++q) {
    const int cb = (w * 4 + q) * 64;           // wave-uniform 16B-chunk base
    __builtin_amdgcn_global_load_lds(
        (const __attribute__((address_space(1))) unsigned int*)(src + (size_t)(cb + l) * 8),
        (__attribute__((address_space(3))) unsigned int*)((char*)dst + (size_t)cb * 16), 16, 0, 0);
  }
}
__device__ __forceinline__ void stage32_256(const f16* __restrict__ src, f16* dst, int t) {
  const int w = t >> 6, l = t & 63;
  #pragma unroll
  for (int q = 0; q < 8; ++q) {
    const int cb = (w * 8 + q) * 64;
    __builtin_amdgcn_global_load_lds(
        (const __attribute__((address_space(1))) unsigned int*)(src + (size_t)(cb + l) * 8),
        (__attribute__((address_space(3))) unsigned int*)((char*)dst + (size_t)cb * 16), 16, 0, 0);
  }
}

template<int NI>
__device__ __forceinline__ void zero_acc(f32x4 (&acc)[NI][4]) {
  #pragma unroll
  for (int i = 0; i < NI; ++i)
    #pragma unroll
    for (int j = 0; j < 4; ++j) acc[i][j] = (f32x4){0.f, 0.f, 0.f, 0.f};
}

// acc += A * B̂^T, both from swizzled LDS (valid as A*B when B̂ symmetric)
template<int NI>
__device__ __forceinline__ void mm_lds(const f16* A, const f16* Bh,
                                       f32x4 (&acc)[NI][4], int w, int l) {
  const int tr0 = (w >> 1) * (16 * NI), tc0 = (w & 1) * 64;
  #pragma unroll
  for (int ks = 0; ks < 4; ++ks) {
    const int kb = ks * 32 + ((l >> 4) << 3);
    f16x8 af[NI], bf[4];
    #pragma unroll
    for (int i = 0; i < NI; ++i) af[i] = *(const f16x8*)(A  + swz(tr0 + i*16 + (l & 15), kb));
    #pragma unroll
    for (int j = 0; j < 4; ++j) bf[j] = *(const f16x8*)(Bh + swz(tc0 + j*16 + (l & 15), kb));
    #pragma unroll
    for (int i = 0; i < NI; ++i)
      #pragma unroll
      for (int j = 0; j < 4; ++j)
        acc[i][j] = __builtin_amdgcn_mfma_f32_16x16x32_f16(af[i], bf[j], acc[i][j], 0, 0, 0);
  }
}

// acc += A * B̂^T with B̂ fragments preloaded (k_apply)
template<int NI>
__device__ __forceinline__ void mm_pre(const f16* A, const f16x8* bfr,
                                       f32x4 (&acc)[NI][4], int w, int l) {
  const int tr0 = (w >> 1) * (16 * NI);
  #pragma unroll
  for (int ks = 0; ks < 4; ++ks) {
    const int kb = ks * 32 + ((l >> 4) << 3);
    f16x8 af[NI];
    #pragma unroll
    for (int i = 0; i < NI; ++i) af[i] = *(const f16x8*)(A + swz(tr0 + i*16 + (l & 15), kb));
    #pragma unroll
    for (int i = 0; i < NI; ++i)
      #pragma unroll
      for (int j = 0; j < 4; ++j)
        acc[i][j] = __builtin_amdgcn_mfma_f32_16x16x32_f16(af[i], bfr[ks*4+j], acc[i][j], 0, 0, 0);
  }
}
// preload B̂ fragments from swizzled-LAYOUT GLOBAL f16 (k_apply G)
__device__ __forceinline__ void pre_bf_gswz(const f16* __restrict__ B, f16x8* bfr, int w, int l) {
  const int tc0 = (w & 1) * 64;
  #pragma unroll
  for (int ks = 0; ks < 4; ++ks) {
    const int kb = ks * 32 + ((l >> 4) << 3);
    #pragma unroll
    for (int j = 0; j < 4; ++j)
      bfr[ks*4+j] = *(const f16x8*)(B + swz(tc0 + j*16 + (l & 15), kb));
  }
}
// preload output-position b64 chunks (transposed convention)
template<int NI>
__device__ __forceinline__ void pre_chunks(const f16* M, f16x4* Cc, int w, int l) {
  const int tr0 = (w >> 1) * (16 * NI), tc0 = (w & 1) * 64;
  #pragma unroll
  for (int i = 0; i < NI; ++i) {
    const int rowb = tr0 + i*16 + ((l >> 4) << 2);
    #pragma unroll
    for (int j = 0; j < 4; ++j)
      Cc[i*4+j] = *(const f16x4*)(M + swz(tc0 + j*16 + (l & 15), rowb));
  }
}

// transpose-packed writeback: buf[swz(col,row)] = alpha*acc + beta*[row==col]
template<int NI>
__device__ __forceinline__ void wb_t(f16* buf, const f32x4 (&acc)[NI][4], int w, int l,
                                     float alpha, float beta) {
  const int tr0 = (w >> 1) * (16 * NI), tc0 = (w & 1) * 64;
  #pragma unroll
  for (int i = 0; i < NI; ++i) {
    const int rowb = tr0 + i*16 + ((l >> 4) << 2);
    #pragma unroll
    for (int j = 0; j < 4; ++j) {
      const int colg = tc0 + j*16 + (l & 15);
      f16x4 h;
      #pragma unroll
      for (int r = 0; r < 4; ++r) {
        float v = alpha * acc[i][j][r];
        if (rowb + r == colg) v += beta;
        h[r] = (f16)v;
      }
      *(f16x4*)(buf + swz(colg, rowb)) = h;
    }
  }
}

// transpose writeback: buf = alpha*acc + d0*I + d1*C1(LDS) + d2*C2(LDS)
template<int NI>
__device__ __forceinline__ void wb_t_gca(f16* buf, const f32x4 (&acc)[NI][4],
                                         const f16* C1, const f16* C2,
                                         int w, int l, float alpha, float d0, float d1, float d2) {
  const int tr0 = (w >> 1) * (16 * NI), tc0 = (w & 1) * 64;
  #pragma unroll
  for (int i = 0; i < NI; ++i) {
    const int rowb = tr0 + i*16 + ((l >> 4) << 2);
    #pragma unroll
    for (int j = 0; j < 4; ++j) {
      const int colg = tc0 + j*16 + (l & 15);
      f16x4 c1 = *(const f16x4*)(C1 + swz(colg, rowb));
      f16x4 c2 = *(const f16x4*)(C2 + swz(colg, rowb));
      f16x4 h;
      #pragma unroll
      for (int r = 0; r < 4; ++r) {
        float v = alpha * acc[i][j][r] + d1 * (float)c1[r] + d2 * (float)c2[r];
        if (rowb + r == colg) v += d0;
        h[r] = (f16)v;
      }
      *(f16x4*)(buf + swz(colg, rowb)) = h;
    }
  }
}

// transpose writeback: v = acc + d0*I + d1*Uc(reg) + d2*U2c(reg) + d3*C3(LDS)
template<int NI>
__device__ __forceinline__ void wb_t_combo3L(f16* buf, const f32x4 (&acc)[NI][4],
                                             const f16x4* Uc, const f16x4* U2c, const f16* C3,
                                             int w, int l, float d0, float d1, float d2, float d3) {
  const int tr0 = (w >> 1) * (16 * NI), tc0 = (w & 1) * 64;
  #pragma unroll
  for (int i = 0; i < NI; ++i) {
    const int rowb = tr0 + i*16 + ((l >> 4) << 2);
    #pragma unroll
    for (int j = 0; j < 4; ++j) {
      const int colg = tc0 + j*16 + (l & 15);
      f16x4 c3 = *(const f16x4*)(C3 + swz(colg, rowb));
      f16x4 h;
      #pragma unroll
      for (int r = 0; r < 4; ++r) {
        float v = acc[i][j][r] + d1 * (float)Uc[i*4+j][r] + d2 * (float)U2c[i*4+j][r]
                               + d3 * (float)c3[r];
        if (rowb + r == colg) v += d0;
        h[r] = (f16)v;
      }
      *(f16x4*)(buf + swz(colg, rowb)) = h;
    }
  }
}

// transpose writeback with combo read from LDS buffers C1,C2 (kD E-step)
template<int NI>
__device__ __forceinline__ void wb_t_gc2s(f16* buf, const f32x4 (&acc)[NI][4],
                                          const f16* C1, const f16* C2,
                                          int w, int l, float d1, float d2, float scale) {
  const int tr0 = (w >> 1) * (16 * NI), tc0 = (w & 1) * 64;
  #pragma unroll
  for (int i = 0; i < NI; ++i) {
    const int rowb = tr0 + i*16 + ((l >> 4) << 2);
    #pragma unroll
    for (int j = 0; j < 4; ++j) {
      const int colg = tc0 + j*16 + (l & 15);
      f16x4 c1 = *(const f16x4*)(C1 + swz(colg, rowb));
      f16x4 c2 = *(const f16x4*)(C2 + swz(colg, rowb));
      f16x4 h;
      #pragma unroll
      for (int r = 0; r < 4; ++r) {
        float v = acc[i][j][r] + d1 * (float)c1[r] + d2 * (float)c2[r];
        if (rowb + r == colg) v += 1.f;
        h[r] = (f16)(v * scale);
      }
      *(f16x4*)(buf + swz(colg, rowb)) = h;
    }
  }
}

// ========== phase A: batch mean + Xh (pre-swizzled f16 copy of X) ==========
__global__ void k_mean_part(const float* __restrict__ X, f16* __restrict__ Xh,
                            float* __restrict__ part, int nper) {
  const int ch = blockIdx.x * 256 + threadIdx.x;   // 0..2047
  const int bc = blockIdx.y;
  const int r = ch >> 4, c8 = (ch & 15) << 3;
  const int dsw = swz(r, c8);
  const float* p = X + (size_t)bc * nper * NN + (size_t)ch * 8;
  f16* xh = Xh + (size_t)bc * nper * NN + dsw;
  f32x4 s0 = {0.f,0.f,0.f,0.f}, s1 = {0.f,0.f,0.f,0.f};
  for (int b = 0; b < nper; ++b) {
    const float* g = p + (size_t)b * NN;
    f32x4 v0 = *(const f32x4*)g;
    f32x4 v1 = *(const f32x4*)(g + 4);
    s0 = s0 + v0; s1 = s1 + v1;
    f16x8 h;
    h[0]=(f16)v0[0]; h[1]=(f16)v0[1]; h[2]=(f16)v0[2]; h[3]=(f16)v0[3];
    h[4]=(f16)v1[0]; h[5]=(f16)v1[1]; h[6]=(f16)v1[2]; h[7]=(f16)v1[3];
    *(f16x8*)(xh + (size_t)b * NN) = h;
  }
  f32x4* pp = (f32x4*)(part + (size_t)bc * NN);
  pp[ch * 2]     = s0;
  pp[ch * 2 + 1] = s1;
}

// ===== stage-1 reduction: 256 slots -> 16 slots =====
__global__ void k_red1(const float* __restrict__ in, float* __restrict__ out) {
  int e4 = blockIdx.x * 256 + threadIdx.x;    // grid (16,16)
  int y = blockIdx.y;
  f32x4 s = {0.f,0.f,0.f,0.f};
  for (int b = 16 * y; b < 16 * y + 16; ++b)
    s = s + ((const f32x4*)in)[(size_t)b * 4096 + e4];
  ((f32x4*)out)[(size_t)y * 4096 + e4] = s;
}

// ====== kB: absorbs final reduction (M0 = sum(part2)*scale) ================
// Cps = M0^{-1/2}, Rh = M0^{1/2} (both single f16).
__global__ __launch_bounds__(512) void kB(
    const float* __restrict__ part2, float scale,
    f16* __restrict__ Cps, f16* __restrict__ Rh) {
  __shared__ __align__(16) f16 A1[NN], A2[NN], A3[NN];
  __shared__ float M0row[NN / 64];   // unused pad guard
  __shared__ float red[128];
  __shared__ float sS;
  const int t = threadIdx.x, w = t >> 6, l = t & 63;
  (void)M0row;
  // M0 -> A1 raw f32->f16? need f32 precision for trace + normalize: store raw
  // f32 into a temporary view over A2+A3 (32KB f32 = 8192 floats... too small).
  // Instead: each thread computes its elements TWICE (cheap, L2-hot 1MB):
  // pass1: trace only; pass2: normalized A1.
  if (t < 128) {
    float s = 0.f;
    for (int b = 0; b < 16; ++b) s += part2[(size_t)b * NN + t * 129];
    red[t] = s * scale;
  }
  __syncthreads();
  for (int s = 64; s > 0; s >>= 1) { if (t < s) red[t] += red[t + s]; __syncthreads(); }
  if (t == 0) sS = red[0] / 128.f;
  __syncthreads();
  const float s = sS, inv = 1.f / s;
  for (int e = t; e < NN; e += 512) {
    int r = e >> 7, c = e & 127;
    float m0 = 0.f;
    for (int b = 0; b < 16; ++b) m0 += part2[(size_t)b * NN + e];
    m0 *= scale;
    A1[swz(r, c)] = (f16)(m0 * inv - (r == c ? 1.f : 0.f));
  }
  __syncthreads();
  f32x4 acc[2][4];
  zero_acc<2>(acc); mm_lds<2>(A1, A1, acc, w, l); wb_t<2>(A2, acc, w, l, 1.f, 0.f); __syncthreads();
  zero_acc<2>(acc); mm_lds<2>(A2, A1, acc, w, l); wb_t<2>(A3, acc, w, l, 1.f, 0.f); __syncthreads();
  const float rs = sqrtf(s), irs = 1.f / rs;
  for (int e = t; e < NN; e += 512) {
    int r = e >> 7, c = e & 127; int ix = swz(r, c);
    float a1 = (float)A1[ix], a2 = (float)A2[ix], a3 = (float)A3[ix];
    float d = (r == c) ? 1.f : 0.f;
    Cps[ix] = (f16)((d - 0.5f*a1 + 0.375f*a2 - 0.3125f*a3) * irs);
    Rh[e]   = (f16)((d + 0.5f*a1 - 0.125f*a2 + 0.0625f*a3) * rs);
  }
}

// ===== phase C: sum of matrix logs — Chebyshev deg-11, PS U^4, single Cp.
// 6 mm-phases/matrix; snapshot folded INTO the fused phase (reads stable
// S0/S2, covered by the fused barrier) — one fewer barrier per matrix.
// Rotation: X/U->S0, T/V->S1, U2/Hnew->S2, H->S3, Cp->S4.
__global__ __launch_bounds__(512) void k_batch_log(
    const f16* __restrict__ Xh, const f16* __restrict__ Cps,
    float* __restrict__ Ppart, int per_blk) {
  __shared__ __align__(16) f16 S0[NN], S1[NN], S2[NN], S3[NN], S4[NN];  // 160 KB
  const int t = threadIdx.x, w = t >> 6, l = t & 63;
  f32x4 lsum[2][4]; zero_acc<2>(lsum);
  f32x4 acc[2][4];
  stage32_512(Xh + (size_t)blockIdx.x * per_blk * NN, S0, t);  // first X
  stage32_512(Cps, S4, t);                                     // Cp, once
  for (int m = 0; m < per_blk; ++m) {
    const size_t b = (size_t)blockIdx.x * per_blk + m;
    asm volatile("s_waitcnt vmcnt(0)" ::: "memory");   // X (and Cp) landed
    __syncthreads();
    // p1: acc = X*Cp^T -> store^T = Cp*X = T -> S1   (X dead after)
    zero_acc<2>(acc); mm_lds<2>(S0, S4, acc, w, l);
    wb_t<2>(S1, acc, w, l, 1.f, 0.f); __syncthreads();
    // p2: acc = T*Cp = B0 -> U = (B0 - m)/h -> S0 (over X)
    zero_acc<2>(acc); mm_lds<2>(S1, S4, acc, w, l);
    wb_t<2>(S0, acc, w, l, 1.f / CHH, -CHM / CHH); __syncthreads();
    // U2 -> S2
    zero_acc<2>(acc); mm_lds<2>(S0, S0, acc, w, l); wb_t<2>(S2, acc, w, l, 1.f, 0.f); __syncthreads();
    // fused phase: FIRST snapshot U,U2 chunks (stable since p2/p3), then
    // U3 = U2*U -> H -> S3; U4 = U2*U2 -> S1 (T dead).  One barrier total.
    f16x4 Uc[8], U2c[8];
    pre_chunks<2>(S0, Uc, w, l);
    pre_chunks<2>(S2, U2c, w, l);
    zero_acc<2>(acc); mm_lds<2>(S2, S0, acc, w, l);
    wb_t_gca<2>(S3, acc, S0, S2, w, l, CB[11], CB[8], CB[9], CB[10]);
    zero_acc<2>(acc); mm_lds<2>(S2, S2, acc, w, l);
    wb_t<2>(S1, acc, w, l, 1.f, 0.f);
    __syncthreads();
    // prefetch next pre-swizzled X DIRECTLY into S0 (H1+final = 2-phase cover)
    if (m + 1 < per_blk) stage32_512(Xh + (b + 1) * NN, S0, t);
    // stored Horner: Hnew = H*V + g1' -> S2 (over U2; combos use regs + S3)
    zero_acc<2>(acc);
    mm_lds<2>(S3, S1, acc, w, l);
    wb_t_combo3L<2>(S2, acc, Uc, U2c, S3, w, l, CF[4], CF[5], CF[6], CF[7]);
    __syncthreads();
    // final: log = Hnew*V + g0', accumulate into lsum (loop-top barrier orders)
    zero_acc<2>(acc);
    mm_lds<2>(S2, S1, acc, w, l);
    {
      const int tr0 = (w >> 1) * 32, tc0 = (w & 1) * 64;
      #pragma unroll
      for (int i = 0; i < 2; ++i) {
        const int rowb = tr0 + i*16 + ((l >> 4) << 2);
        #pragma unroll
        for (int j = 0; j < 4; ++j) {
          const int colg = tc0 + j*16 + (l & 15);
          f16x4 c3 = *(const f16x4*)(S3 + swz(colg, rowb));
          #pragma unroll
          for (int r = 0; r < 4; ++r) {
            float v = acc[i][j][r] + CF[1] * (float)Uc[i*4+j][r]
                    + CF[2] * (float)U2c[i*4+j][r] + CF[3] * (float)c3[r];
            if (rowb + r == colg) v += CF[0];
            lsum[i][j][r] += v;
          }
        }
      }
    }
  }
  __syncthreads();
  float* pp = Ppart + (size_t)blockIdx.x * NN;
  const int tr0 = (w >> 1) * 32, tc0 = (w & 1) * 64;
  #pragma unroll
  for (int i = 0; i < 2; ++i) {
    const int rowb = tr0 + i*16 + ((l >> 4) << 2);
    #pragma unroll
    for (int j = 0; j < 4; ++j) {
      const int colg = tc0 + j*16 + (l & 15);
      *(f32x4*)(pp + colg * 128 + rowb) = lsum[i][j];
    }
  }
}

// ========= kD: absorbs final reduction (P = sum(part2)*scale). =============
// Single-f16 chain: E=exp(P) deg-4 PS, BM=R E R, S=BM^{-1/2} deg-3,
// T=mean^{1/2} deg-2, G=T*S.  Q folded into D2 writeback.
__global__ __launch_bounds__(512) void kD(
    const float* __restrict__ part2, float scale, const float* __restrict__ mean,
    const f16* __restrict__ Rh, f16* __restrict__ Gs) {
  __shared__ __align__(16) f16 B1[NN], B2[NN], B3[NN], B4[NN];
  __shared__ float red[128];
  __shared__ float sv;
  const int t = threadIdx.x, w = t >> 6, l = t & 63;
  f32x4 acc[2][4];
  // mu = tr(P)/128 from part2
  if (t < 128) {
    float s = 0.f;
    for (int b = 0; b < 16; ++b) s += part2[(size_t)b * NN + t * 129];
    red[t] = s * scale;
  }
  __syncthreads();
  for (int s = 64; s > 0; s >>= 1) { if (t < s) red[t] += red[t + s]; __syncthreads(); }
  if (t == 0) sv = red[0] / 128.f;
  __syncthreads();
  const float mu = sv;
  for (int e = t; e < NN; e += 512) {
    int r = e >> 7, c = e & 127;
    float p = 0.f;
    for (int b = 0; b < 16; ++b) p += part2[(size_t)b * NN + e];
    p *= scale;
    B1[swz(r, c)] = (f16)(p - (r == c ? mu : 0.f));
  }
  __syncthreads();
  // D2 -> B2 AND Q = D/6 + D2/24 -> B3 (dual writeback, one barrier)
  zero_acc<2>(acc); mm_lds<2>(B1, B1, acc, w, l);
  {
    const int tr0 = (w >> 1) * 32, tc0 = (w & 1) * 64;
    #pragma unroll
    for (int i = 0; i < 2; ++i) {
      const int rowb = tr0 + i*16 + ((l >> 4) << 2);
      #pragma unroll
      for (int j = 0; j < 4; ++j) {
        const int colg = tc0 + j*16 + (l & 15);
        f16x4 dc = *(const f16x4*)(B1 + swz(colg, rowb));
        f16x4 h2, hq;
        #pragma unroll
        for (int r = 0; r < 4; ++r) {
          float v = acc[i][j][r];
          h2[r] = (f16)v;
          hq[r] = (f16)((1.f/24.f) * v + (1.f/6.f) * (float)dc[r]);
        }
        *(f16x4*)(B2 + swz(colg, rowb)) = h2;
        *(f16x4*)(B3 + swz(colg, rowb)) = hq;
      }
    }
  }
  __syncthreads();
  zero_acc<2>(acc); mm_lds<2>(B2, B3, acc, w, l); __syncthreads();
  wb_t_gc2s<2>(B3, acc, B1, B2, w, l, 1.f, 0.5f, expf(mu));
  __syncthreads();
  load_g2l_h(Rh, B4, t, 512);
  __syncthreads();
  zero_acc<2>(acc); mm_lds<2>(B3, B4, acc, w, l);
  wb_t<2>(B1, acc, w, l, 1.f, 0.f); __syncthreads();
  zero_acc<2>(acc); mm_lds<2>(B4, B1, acc, w, l);
  wb_t<2>(B2, acc, w, l, 1.f, 0.f); __syncthreads();
  if (t < 128) red[t] = (float)B2[swz(t, t)];
  __syncthreads();
  for (int s = 64; s > 0; s >>= 1) { if (t < s) red[t] += red[t + s]; __syncthreads(); }
  if (t == 0) sv = red[0] / 128.f;
  __syncthreads();
  const float s2 = sv, inv2 = 1.f / s2;
  for (int e = t; e < NN; e += 512) {
    int r = e >> 7, c = e & 127; int ix = swz(r, c);
    B2[ix] = (f16)((float)B2[ix] * inv2 - (r == c ? 1.f : 0.f));
  }
  __syncthreads();
  zero_acc<2>(acc); mm_lds<2>(B2, B2, acc, w, l); wb_t<2>(B1, acc, w, l, 1.f, 0.f); __syncthreads();
  zero_acc<2>(acc); mm_lds<2>(B1, B2, acc, w, l); wb_t<2>(B3, acc, w, l, 1.f, 0.f); __syncthreads();
  {
    const float is2 = 1.f / sqrtf(s2);
    for (int e = t; e < NN; e += 512) {
      int r = e >> 7, c = e & 127; int ix = swz(r, c);
      float f1 = (float)B2[ix], f2 = (float)B1[ix], f3 = (float)B3[ix];
      float d = (r == c) ? 1.f : 0.f;
      B4[ix] = (f16)((d - 0.5f*f1 + 0.375f*f2 - 0.3125f*f3) * is2);
    }
  }
  __syncthreads();
  if (t < 128) red[t] = mean[t * 129];
  __syncthreads();
  for (int s = 64; s > 0; s >>= 1) { if (t < s) red[t] += red[t + s]; __syncthreads(); }
  if (t == 0) sv = red[0] / 128.f;
  __syncthreads();
  const float s3 = sv, inv3 = 1.f / s3;
  for (int e = t; e < NN; e += 512) {
    int r = e >> 7, c = e & 127;
    B1[swz(r, c)] = (f16)(mean[e] * inv3 - (r == c ? 1.f : 0.f));
  }
  __syncthreads();
  zero_acc<2>(acc); mm_lds<2>(B1, B1, acc, w, l); wb_t<2>(B2, acc, w, l, 1.f, 0.f); __syncthreads();
  {
    const float rs3 = sqrtf(s3);
    for (int e = t; e < NN; e += 512) {
      int r = e >> 7, c = e & 127; int ix = swz(r, c);
      float m1 = (float)B1[ix], m2 = (float)B2[ix];
      float d = (r == c) ? 1.f : 0.f;
      B3[ix] = (f16)((d + 0.5f*m1 - 0.125f*m2) * rs3);
    }
  }
  __syncthreads();
  zero_acc<2>(acc); mm_lds<2>(B4, B3, acc, w, l);
  {
    const int tr0 = (w >> 1) * 32, tc0 = (w & 1) * 64;
    #pragma unroll
    for (int i = 0; i < 2; ++i) {
      const int rowb = tr0 + i*16 + ((l >> 4) << 2);
      #pragma unroll
      for (int j = 0; j < 4; ++j) {
        const int colg = tc0 + j*16 + (l & 15);
        f16x4 h;
        #pragma unroll
        for (int r = 0; r < 4; ++r) h[r] = (f16)acc[i][j][r];
        *(f16x4*)(Gs + swz(colg, rowb)) = h;
      }
    }
  }
}

// =================== phase E: Xn = G * X * G^T ===================
__global__ __launch_bounds__(256, 1) void k_apply(
    const f16* __restrict__ Xh, const f16* __restrict__ Gs,
    float* __restrict__ Out, int per_blk) {
  __shared__ __align__(16) f16 SX[NN];
  const int t = threadIdx.x, w = t >> 6, l = t & 63;
  f16x8 bg[16];
  pre_bf_gswz(Gs, bg, w, l);
  f32x4 acc[4][4];
  for (int m = 0; m < per_blk; ++m) {
    const size_t b = (size_t)blockIdx.x * per_blk + m;
    stage32_256(Xh + b * NN, SX, t);
    asm volatile("s_waitcnt vmcnt(0)" ::: "memory");
    __syncthreads();
    zero_acc<4>(acc); mm_pre<4>(SX, bg, acc, w, l);
    __syncthreads();
    wb_t<4>(SX, acc, w, l, 1.f, 0.f);      // SX := (X*G^T)^T = G*X = T
    __syncthreads();
    zero_acc<4>(acc); mm_pre<4>(SX, bg, acc, w, l);
    float* O = Out + b * NN;
    const int tr0 = (w >> 1) * 64, tc0 = (w & 1) * 64;
    #pragma unroll
    for (int i = 0; i < 4; ++i) {
      const int rowb = tr0 + i*16 + ((l >> 4) << 2);
      #pragma unroll
      for (int j = 0; j < 4; ++j) {
        const int colg = tc0 + j*16 + (l & 15);
        *(f32x4*)(O + colg * 128 + rowb) = acc[i][j];
      }
    }
    __syncthreads();
  }
}

// =================== host ===================
extern "C" void kernel_launch(void* const* d_in, const int* in_sizes, int n_in,
                              void* d_out, int out_size, void* d_ws, size_t ws_size,
                              hipStream_t stream) {
  const float* X    = (const float*)d_in[0];
  const float* mean = (const float*)d_in[1];
  // d_in[2] (running_mean) mathematically unused: eta=1.0 makes
  // rm_sqrt @ powm(rm_invsqrt@BM@rm_invsqrt, 1) @ rm_sqrt == BM for ANY SPD rm.
  const int Bn = in_sizes[0] / NN;       // 2048

  float* wsf = (float*)d_ws;
  f16* hbase = (f16*)(wsf + 2 * (size_t)NN);
  f16 *Cps = hbase;                      // swizzled single-f16 Cp
  f16 *Rh  = hbase + NN;                 // row-major single-f16 R
  f16 *Gs  = hbase + 2 * NN;             // swizzled single-f16 G
  float* Ppart = wsf + 4 * (size_t)NN;            // 256 slots (16 MB)
  float* part2 = wsf + (4 + 256) * (size_t)NN;    // 16 slots (1 MB)
  f16* Xh = (f16*)(wsf + (4 + 256 + 16) * (size_t)NN);  // 64 MB pre-swizzled f16 X

  const float invBn = 1.f / (float)Bn;
  k_mean_part<<<dim3(8, 256), 256, 0, stream>>>(X, Xh, Ppart, Bn / 256);
  k_red1<<<dim3(16, 16), 256, 0, stream>>>(Ppart, part2);
  kB<<<1, 512, 0, stream>>>(part2, invBn, Cps, Rh);
  k_batch_log<<<256, 512, 0, stream>>>(Xh, Cps, Ppart, Bn / 256);
  k_red1<<<dim3(16, 16), 256, 0, stream>>>(Ppart, part2);
  kD<<<1, 512, 0, stream>>>(part2, invBn, mean, Rh, Gs);
  k_apply<<<2048, 256, 0, stream>>>(Xh, Gs, (float*)d_out, Bn / 2048);
}

// Round 19
// 221.621 us; speedup vs baseline: 1.1320x; 1.1320x over previous
//
#include <hip/hip_runtime.h>

typedef _Float16 f16;
typedef _Float16 f16x8 __attribute__((ext_vector_type(8)));
typedef _Float16 f16x4 __attribute__((ext_vector_type(4)));
typedef float    f32x4 __attribute__((ext_vector_type(4)));

#define NN 16384   // 128*128

// ---- Chebyshev deg-11 approx of log(x) on x in [0.3, 3.5] (verified r11) ---
#define CHM 1.9f
#define CHH 1.6f
__device__ __constant__ float CB[12] = {
   0.6419309f,  0.8414791f, -0.3609340f,  0.2147234f,   // g0: b0..b3
  -0.0582120f, -0.0285232f, -0.3102016f,  0.3787296f,   // g1: b4..b7
   0.3577728f, -0.4226304f, -0.2457600f,  0.2444390f }; // g2: b8..b11
// Folded combos for H-substitution (U3 = (H - b8 I - b9 U - b10 U2)/b11):
//  g0' = e0 I + e1 U + e2 U2 + e3 H ;  g1' = c0 I + c1 U + c2 U2 + c3 H.
// Hand-verified at t=0 and t=1 vs original polynomial (residual <= 7e-7).
__device__ __constant__ float CF[8] = {
   0.3276514f,  1.2127320f, -0.1450500f,  0.8784340f,   // e0..e3 (final)
  -0.6125382f,  0.6262931f,  0.0705748f,  1.5493830f }; // c0..c3 (stored Horner)

// ---------------- swizzled LDS index for 128x128 f16 (G4 XOR pattern) -------
__device__ __forceinline__ int swz(int r, int c) {
  return (r << 7) + ((((c >> 3) ^ (r & 7)) << 3) | (c & 7));
}

// load 128x128 f16 (global, row-major) -> swizzled LDS (kD only)
__device__ __forceinline__ void load_g2l_h(const f16* __restrict__ G, f16* buf, int t, int nt) {
  for (int ch = t; ch < 2048; ch += nt) {
    int r = ch >> 4, c8 = (ch & 15) << 3;
    *(f16x8*)(buf + swz(r, c8)) = *(const f16x8*)(G + (r << 7) + c8);
  }
}

// async stage of a PRE-SWIZZLED 32KB f16 matrix -> LDS (linear copy).
__device__ __forceinline__ void stage32_512(const f16* __restrict__ src, f16* dst, int t) {
  const int w = t >> 6, l = t & 63;
  #pragma unroll
  for (int q = 0; q < 4; ++q) {
    const int cb = (w * 4 + q) * 64;           // wave-uniform 16B-chunk base
    __builtin_amdgcn_global_load_lds(
        (const __attribute__((address_space(1))) unsigned int*)(src + (size_t)(cb + l) * 8),
        (__attribute__((address_space(3))) unsigned int*)((char*)dst + (size_t)cb * 16), 16, 0, 0);
  }
}
__device__ __forceinline__ void stage32_256(const f16* __restrict__ src, f16* dst, int t) {
  const int w = t >> 6, l = t & 63;
  #pragma unroll
  for (int q = 0; q < 8; ++q) {
    const int cb = (w * 8 + q) * 64;
    __builtin_amdgcn_global_load_lds(
        (const __attribute__((address_space(1))) unsigned int*)(src + (size_t)(cb + l) * 8),
        (__attribute__((address_space(3))) unsigned int*)((char*)dst + (size_t)cb * 16), 16, 0, 0);
  }
}

template<int NI>
__device__ __forceinline__ void zero_acc(f32x4 (&acc)[NI][4]) {
  #pragma unroll
  for (int i = 0; i < NI; ++i)
    #pragma unroll
    for (int j = 0; j < 4; ++j) acc[i][j] = (f32x4){0.f, 0.f, 0.f, 0.f};
}

// acc += A * B̂^T, both from swizzled LDS (valid as A*B when B̂ symmetric)
template<int NI>
__device__ __forceinline__ void mm_lds(const f16* A, const f16* Bh,
                                       f32x4 (&acc)[NI][4], int w, int l) {
  const int tr0 = (w >> 1) * (16 * NI), tc0 = (w & 1) * 64;
  #pragma unroll
  for (int ks = 0; ks < 4; ++ks) {
    const int kb = ks * 32 + ((l >> 4) << 3);
    f16x8 af[NI], bf[4];
    #pragma unroll
    for (int i = 0; i < NI; ++i) af[i] = *(const f16x8*)(A  + swz(tr0 + i*16 + (l & 15), kb));
    #pragma unroll
    for (int j = 0; j < 4; ++j) bf[j] = *(const f16x8*)(Bh + swz(tc0 + j*16 + (l & 15), kb));
    #pragma unroll
    for (int i = 0; i < NI; ++i)
      #pragma unroll
      for (int j = 0; j < 4; ++j)
        acc[i][j] = __builtin_amdgcn_mfma_f32_16x16x32_f16(af[i], bf[j], acc[i][j], 0, 0, 0);
  }
}

// acc += A * B̂^T with B̂ fragments preloaded (k_apply)
template<int NI>
__device__ __forceinline__ void mm_pre(const f16* A, const f16x8* bfr,
                                       f32x4 (&acc)[NI][4], int w, int l) {
  const int tr0 = (w >> 1) * (16 * NI);
  #pragma unroll
  for (int ks = 0; ks < 4; ++ks) {
    const int kb = ks * 32 + ((l >> 4) << 3);
    f16x8 af[NI];
    #pragma unroll
    for (int i = 0; i < NI; ++i) af[i] = *(const f16x8*)(A + swz(tr0 + i*16 + (l & 15), kb));
    #pragma unroll
    for (int i = 0; i < NI; ++i)
      #pragma unroll
      for (int j = 0; j < 4; ++j)
        acc[i][j] = __builtin_amdgcn_mfma_f32_16x16x32_f16(af[i], bfr[ks*4+j], acc[i][j], 0, 0, 0);
  }
}
// preload B̂ fragments from swizzled-LAYOUT GLOBAL f16 (k_apply G)
__device__ __forceinline__ void pre_bf_gswz(const f16* __restrict__ B, f16x8* bfr, int w, int l) {
  const int tc0 = (w & 1) * 64;
  #pragma unroll
  for (int ks = 0; ks < 4; ++ks) {
    const int kb = ks * 32 + ((l >> 4) << 3);
    #pragma unroll
    for (int j = 0; j < 4; ++j)
      bfr[ks*4+j] = *(const f16x8*)(B + swz(tc0 + j*16 + (l & 15), kb));
  }
}
// preload output-position b64 chunks (transposed convention)
template<int NI>
__device__ __forceinline__ void pre_chunks(const f16* M, f16x4* Cc, int w, int l) {
  const int tr0 = (w >> 1) * (16 * NI), tc0 = (w & 1) * 64;
  #pragma unroll
  for (int i = 0; i < NI; ++i) {
    const int rowb = tr0 + i*16 + ((l >> 4) << 2);
    #pragma unroll
    for (int j = 0; j < 4; ++j)
      Cc[i*4+j] = *(const f16x4*)(M + swz(tc0 + j*16 + (l & 15), rowb));
  }
}

// transpose-packed writeback: buf[swz(col,row)] = alpha*acc + beta*[row==col]
template<int NI>
__device__ __forceinline__ void wb_t(f16* buf, const f32x4 (&acc)[NI][4], int w, int l,
                                     float alpha, float beta) {
  const int tr0 = (w >> 1) * (16 * NI), tc0 = (w & 1) * 64;
  #pragma unroll
  for (int i = 0; i < NI; ++i) {
    const int rowb = tr0 + i*16 + ((l >> 4) << 2);
    #pragma unroll
    for (int j = 0; j < 4; ++j) {
      const int colg = tc0 + j*16 + (l & 15);
      f16x4 h;
      #pragma unroll
      for (int r = 0; r < 4; ++r) {
        float v = alpha * acc[i][j][r];
        if (rowb + r == colg) v += beta;
        h[r] = (f16)v;
      }
      *(f16x4*)(buf + swz(colg, rowb)) = h;
    }
  }
}

// transpose writeback: buf = alpha*acc + d0*I + d1*C1(LDS) + d2*C2(LDS)
template<int NI>
__device__ __forceinline__ void wb_t_gca(f16* buf, const f32x4 (&acc)[NI][4],
                                         const f16* C1, const f16* C2,
                                         int w, int l, float alpha, float d0, float d1, float d2) {
  const int tr0 = (w >> 1) * (16 * NI), tc0 = (w & 1) * 64;
  #pragma unroll
  for (int i = 0; i < NI; ++i) {
    const int rowb = tr0 + i*16 + ((l >> 4) << 2);
    #pragma unroll
    for (int j = 0; j < 4; ++j) {
      const int colg = tc0 + j*16 + (l & 15);
      f16x4 c1 = *(const f16x4*)(C1 + swz(colg, rowb));
      f16x4 c2 = *(const f16x4*)(C2 + swz(colg, rowb));
      f16x4 h;
      #pragma unroll
      for (int r = 0; r < 4; ++r) {
        float v = alpha * acc[i][j][r] + d1 * (float)c1[r] + d2 * (float)c2[r];
        if (rowb + r == colg) v += d0;
        h[r] = (f16)v;
      }
      *(f16x4*)(buf + swz(colg, rowb)) = h;
    }
  }
}

// transpose writeback: v = acc + d0*I + d1*Uc(reg) + d2*U2c(reg) + d3*C3(LDS)
template<int NI>
__device__ __forceinline__ void wb_t_combo3L(f16* buf, const f32x4 (&acc)[NI][4],
                                             const f16x4* Uc, const f16x4* U2c, const f16* C3,
                                             int w, int l, float d0, float d1, float d2, float d3) {
  const int tr0 = (w >> 1) * (16 * NI), tc0 = (w & 1) * 64;
  #pragma unroll
  for (int i = 0; i < NI; ++i) {
    const int rowb = tr0 + i*16 + ((l >> 4) << 2);
    #pragma unroll
    for (int j = 0; j < 4; ++j) {
      const int colg = tc0 + j*16 + (l & 15);
      f16x4 c3 = *(const f16x4*)(C3 + swz(colg, rowb));
      f16x4 h;
      #pragma unroll
      for (int r = 0; r < 4; ++r) {
        float v = acc[i][j][r] + d1 * (float)Uc[i*4+j][r] + d2 * (float)U2c[i*4+j][r]
                               + d3 * (float)c3[r];
        if (rowb + r == colg) v += d0;
        h[r] = (f16)v;
      }
      *(f16x4*)(buf + swz(colg, rowb)) = h;
    }
  }
}

// transpose writeback with combo read from LDS buffers C1,C2 (kD E-step)
template<int NI>
__device__ __forceinline__ void wb_t_gc2s(f16* buf, const f32x4 (&acc)[NI][4],
                                          const f16* C1, const f16* C2,
                                          int w, int l, float d1, float d2, float scale) {
  const int tr0 = (w >> 1) * (16 * NI), tc0 = (w & 1) * 64;
  #pragma unroll
  for (int i = 0; i < NI; ++i) {
    const int rowb = tr0 + i*16 + ((l >> 4) << 2);
    #pragma unroll
    for (int j = 0; j < 4; ++j) {
      const int colg = tc0 + j*16 + (l & 15);
      f16x4 c1 = *(const f16x4*)(C1 + swz(colg, rowb));
      f16x4 c2 = *(const f16x4*)(C2 + swz(colg, rowb));
      f16x4 h;
      #pragma unroll
      for (int r = 0; r < 4; ++r) {
        float v = acc[i][j][r] + d1 * (float)c1[r] + d2 * (float)c2[r];
        if (rowb + r == colg) v += 1.f;
        h[r] = (f16)(v * scale);
      }
      *(f16x4*)(buf + swz(colg, rowb)) = h;
    }
  }
}

// ========== phase A: batch mean + Xh (pre-swizzled f16 copy of X) ==========
__global__ void k_mean_part(const float* __restrict__ X, f16* __restrict__ Xh,
                            float* __restrict__ part, int nper) {
  const int ch = blockIdx.x * 256 + threadIdx.x;   // 0..2047
  const int bc = blockIdx.y;
  const int r = ch >> 4, c8 = (ch & 15) << 3;
  const int dsw = swz(r, c8);
  const float* p = X + (size_t)bc * nper * NN + (size_t)ch * 8;
  f16* xh = Xh + (size_t)bc * nper * NN + dsw;
  f32x4 s0 = {0.f,0.f,0.f,0.f}, s1 = {0.f,0.f,0.f,0.f};
  for (int b = 0; b < nper; ++b) {
    const float* g = p + (size_t)b * NN;
    f32x4 v0 = *(const f32x4*)g;
    f32x4 v1 = *(const f32x4*)(g + 4);
    s0 = s0 + v0; s1 = s1 + v1;
    f16x8 h;
    h[0]=(f16)v0[0]; h[1]=(f16)v0[1]; h[2]=(f16)v0[2]; h[3]=(f16)v0[3];
    h[4]=(f16)v1[0]; h[5]=(f16)v1[1]; h[6]=(f16)v1[2]; h[7]=(f16)v1[3];
    *(f16x8*)(xh + (size_t)b * NN) = h;
  }
  f32x4* pp = (f32x4*)(part + (size_t)bc * NN);
  pp[ch * 2]     = s0;
  pp[ch * 2 + 1] = s1;
}

// ===== two-stage 256-slot reduction (r18 lesson: do NOT absorb stage 2 into
// the single-block kernels — one block reading 2MB of partials costs ~25us) ==
__global__ void k_red1(const float* __restrict__ in, float* __restrict__ out) {
  int e4 = blockIdx.x * 256 + threadIdx.x;    // grid (16,16)
  int y = blockIdx.y;
  f32x4 s = {0.f,0.f,0.f,0.f};
  for (int b = 16 * y; b < 16 * y + 16; ++b)
    s = s + ((const f32x4*)in)[(size_t)b * 4096 + e4];
  ((f32x4*)out)[(size_t)y * 4096 + e4] = s;
}
__global__ void k_red2(const float* __restrict__ in, float* __restrict__ out, float scale) {
  int e4 = blockIdx.x * 256 + threadIdx.x;    // 16 blocks
  f32x4 s = {0.f,0.f,0.f,0.f};
  for (int b = 0; b < 16; ++b) s = s + ((const f32x4*)in)[(size_t)b * 4096 + e4];
  ((f32x4*)out)[e4] = s * scale;
}

// ====== kB: Cps = M0^{-1/2}, Rh = M0^{1/2} (both single f16) ================
__global__ __launch_bounds__(512) void kB(
    const float* __restrict__ M0, f16* __restrict__ Cps, f16* __restrict__ Rh) {
  __shared__ __align__(16) f16 A1[NN], A2[NN], A3[NN];
  __shared__ float red[128];
  __shared__ float sS;
  const int t = threadIdx.x, w = t >> 6, l = t & 63;
  if (t < 128) red[t] = M0[t * 129];
  __syncthreads();
  for (int s = 64; s > 0; s >>= 1) { if (t < s) red[t] += red[t + s]; __syncthreads(); }
  if (t == 0) sS = red[0] / 128.f;
  __syncthreads();
  const float s = sS, inv = 1.f / s;
  for (int e = t; e < NN; e += 512) {
    int r = e >> 7, c = e & 127;
    A1[swz(r, c)] = (f16)(M0[e] * inv - (r == c ? 1.f : 0.f));
  }
  __syncthreads();
  f32x4 acc[2][4];
  zero_acc<2>(acc); mm_lds<2>(A1, A1, acc, w, l); wb_t<2>(A2, acc, w, l, 1.f, 0.f); __syncthreads();
  zero_acc<2>(acc); mm_lds<2>(A2, A1, acc, w, l); wb_t<2>(A3, acc, w, l, 1.f, 0.f); __syncthreads();
  const float rs = sqrtf(s), irs = 1.f / rs;
  for (int e = t; e < NN; e += 512) {
    int r = e >> 7, c = e & 127; int ix = swz(r, c);
    float a1 = (float)A1[ix], a2 = (float)A2[ix], a3 = (float)A3[ix];
    float d = (r == c) ? 1.f : 0.f;
    Cps[ix] = (f16)((d - 0.5f*a1 + 0.375f*a2 - 0.3125f*a3) * irs);
    Rh[e]   = (f16)((d + 0.5f*a1 - 0.125f*a2 + 0.0625f*a3) * rs);
  }
}

// ===== phase C: sum of matrix logs — Chebyshev deg-11, PS U^4, single Cp.
// 6 mm-phases/matrix (r17-proven form: separate snapshot barrier — the fold
// into the fused phase regressed in r18).  Cp resident in S4 (once/block);
// next-X prefetches straight into S0 (dead after snapshot; 2-phase cover).
__global__ __launch_bounds__(512) void k_batch_log(
    const f16* __restrict__ Xh, const f16* __restrict__ Cps,
    float* __restrict__ Ppart, int per_blk) {
  __shared__ __align__(16) f16 S0[NN], S1[NN], S2[NN], S3[NN], S4[NN];  // 160 KB
  const int t = threadIdx.x, w = t >> 6, l = t & 63;
  f32x4 lsum[2][4]; zero_acc<2>(lsum);
  f32x4 acc[2][4];
  stage32_512(Xh + (size_t)blockIdx.x * per_blk * NN, S0, t);  // first X
  stage32_512(Cps, S4, t);                                     // Cp, once
  for (int m = 0; m < per_blk; ++m) {
    const size_t b = (size_t)blockIdx.x * per_blk + m;
    asm volatile("s_waitcnt vmcnt(0)" ::: "memory");   // X (and Cp) landed
    __syncthreads();
    // p1: acc = X*Cp^T -> store^T = Cp*X = T -> S1   (X dead after)
    zero_acc<2>(acc); mm_lds<2>(S0, S4, acc, w, l);
    wb_t<2>(S1, acc, w, l, 1.f, 0.f); __syncthreads();
    // p2: acc = T*Cp = B0 -> U = (B0 - m)/h -> S0 (over X)
    zero_acc<2>(acc); mm_lds<2>(S1, S4, acc, w, l);
    wb_t<2>(S0, acc, w, l, 1.f / CHH, -CHM / CHH); __syncthreads();
    // U2 -> S2
    zero_acc<2>(acc); mm_lds<2>(S0, S0, acc, w, l); wb_t<2>(S2, acc, w, l, 1.f, 0.f); __syncthreads();
    // fused: U3 = U2*U -> H = b11*U3 + b8 I + b9 U + b10 U2 -> S3;
    //        U4 = U2*U2 -> S1 (T dead).  One barrier.
    zero_acc<2>(acc); mm_lds<2>(S2, S0, acc, w, l);
    wb_t_gca<2>(S3, acc, S0, S2, w, l, CB[11], CB[8], CB[9], CB[10]);
    zero_acc<2>(acc); mm_lds<2>(S2, S2, acc, w, l);
    wb_t<2>(S1, acc, w, l, 1.f, 0.f);
    __syncthreads();
    // snapshot U,U2 combo chunks; then S0 is fully dead
    f16x4 Uc[8], U2c[8];
    pre_chunks<2>(S0, Uc, w, l);
    pre_chunks<2>(S2, U2c, w, l);
    __syncthreads();
    // prefetch next pre-swizzled X DIRECTLY into S0 (H1+final = 2-phase cover)
    if (m + 1 < per_blk) stage32_512(Xh + (b + 1) * NN, S0, t);
    // stored Horner: Hnew = H*V + g1' -> S2 (over U2; combos use regs + S3)
    zero_acc<2>(acc);
    mm_lds<2>(S3, S1, acc, w, l);
    wb_t_combo3L<2>(S2, acc, Uc, U2c, S3, w, l, CF[4], CF[5], CF[6], CF[7]);
    __syncthreads();
    // final: log = Hnew*V + g0', accumulate into lsum (loop-top barrier orders)
    zero_acc<2>(acc);
    mm_lds<2>(S2, S1, acc, w, l);
    {
      const int tr0 = (w >> 1) * 32, tc0 = (w & 1) * 64;
      #pragma unroll
      for (int i = 0; i < 2; ++i) {
        const int rowb = tr0 + i*16 + ((l >> 4) << 2);
        #pragma unroll
        for (int j = 0; j < 4; ++j) {
          const int colg = tc0 + j*16 + (l & 15);
          f16x4 c3 = *(const f16x4*)(S3 + swz(colg, rowb));
          #pragma unroll
          for (int r = 0; r < 4; ++r) {
            float v = acc[i][j][r] + CF[1] * (float)Uc[i*4+j][r]
                    + CF[2] * (float)U2c[i*4+j][r] + CF[3] * (float)c3[r];
            if (rowb + r == colg) v += CF[0];
            lsum[i][j][r] += v;
          }
        }
      }
    }
  }
  __syncthreads();
  float* pp = Ppart + (size_t)blockIdx.x * NN;
  const int tr0 = (w >> 1) * 32, tc0 = (w & 1) * 64;
  #pragma unroll
  for (int i = 0; i < 2; ++i) {
    const int rowb = tr0 + i*16 + ((l >> 4) << 2);
    #pragma unroll
    for (int j = 0; j < 4; ++j) {
      const int colg = tc0 + j*16 + (l & 15);
      *(f32x4*)(pp + colg * 128 + rowb) = lsum[i][j];
    }
  }
}

// ========= kD: single-f16 chain — E=exp(P) deg-4 PS, BM=R E R, =============
// S=BM^{-1/2} deg-3, T=mean^{1/2} deg-2, G=T*S.  Q folded into D2 writeback.
__global__ __launch_bounds__(512) void kD(
    const float* __restrict__ P, const float* __restrict__ mean,
    const f16* __restrict__ Rh, f16* __restrict__ Gs) {
  __shared__ __align__(16) f16 B1[NN], B2[NN], B3[NN], B4[NN];
  __shared__ float red[128];
  __shared__ float sv;
  const int t = threadIdx.x, w = t >> 6, l = t & 63;
  f32x4 acc[2][4];
  if (t < 128) red[t] = P[t * 129];
  __syncthreads();
  for (int s = 64; s > 0; s >>= 1) { if (t < s) red[t] += red[t + s]; __syncthreads(); }
  if (t == 0) sv = red[0] / 128.f;
  __syncthreads();
  const float mu = sv;
  for (int e = t; e < NN; e += 512) {
    int r = e >> 7, c = e & 127;
    B1[swz(r, c)] = (f16)(P[e] - (r == c ? mu : 0.f));
  }
  __syncthreads();
  // D2 -> B2 AND Q = D/6 + D2/24 -> B3 (dual writeback, one barrier)
  zero_acc<2>(acc); mm_lds<2>(B1, B1, acc, w, l);
  {
    const int tr0 = (w >> 1) * 32, tc0 = (w & 1) * 64;
    #pragma unroll
    for (int i = 0; i < 2; ++i) {
      const int rowb = tr0 + i*16 + ((l >> 4) << 2);
      #pragma unroll
      for (int j = 0; j < 4; ++j) {
        const int colg = tc0 + j*16 + (l & 15);
        f16x4 dc = *(const f16x4*)(B1 + swz(colg, rowb));
        f16x4 h2, hq;
        #pragma unroll
        for (int r = 0; r < 4; ++r) {
          float v = acc[i][j][r];
          h2[r] = (f16)v;
          hq[r] = (f16)((1.f/24.f) * v + (1.f/6.f) * (float)dc[r]);
        }
        *(f16x4*)(B2 + swz(colg, rowb)) = h2;
        *(f16x4*)(B3 + swz(colg, rowb)) = hq;
      }
    }
  }
  __syncthreads();
  zero_acc<2>(acc); mm_lds<2>(B2, B3, acc, w, l); __syncthreads();
  wb_t_gc2s<2>(B3, acc, B1, B2, w, l, 1.f, 0.5f, expf(mu));
  __syncthreads();
  load_g2l_h(Rh, B4, t, 512);
  __syncthreads();
  zero_acc<2>(acc); mm_lds<2>(B3, B4, acc, w, l);
  wb_t<2>(B1, acc, w, l, 1.f, 0.f); __syncthreads();
  zero_acc<2>(acc); mm_lds<2>(B4, B1, acc, w, l);
  wb_t<2>(B2, acc, w, l, 1.f, 0.f); __syncthreads();
  if (t < 128) red[t] = (float)B2[swz(t, t)];
  __syncthreads();
  for (int s = 64; s > 0; s >>= 1) { if (t < s) red[t] += red[t + s]; __syncthreads(); }
  if (t == 0) sv = red[0] / 128.f;
  __syncthreads();
  const float s2 = sv, inv2 = 1.f / s2;
  for (int e = t; e < NN; e += 512) {
    int r = e >> 7, c = e & 127; int ix = swz(r, c);
    B2[ix] = (f16)((float)B2[ix] * inv2 - (r == c ? 1.f : 0.f));
  }
  __syncthreads();
  zero_acc<2>(acc); mm_lds<2>(B2, B2, acc, w, l); wb_t<2>(B1, acc, w, l, 1.f, 0.f); __syncthreads();
  zero_acc<2>(acc); mm_lds<2>(B1, B2, acc, w, l); wb_t<2>(B3, acc, w, l, 1.f, 0.f); __syncthreads();
  {
    const float is2 = 1.f / sqrtf(s2);
    for (int e = t; e < NN; e += 512) {
      int r = e >> 7, c = e & 127; int ix = swz(r, c);
      float f1 = (float)B2[ix], f2 = (float)B1[ix], f3 = (float)B3[ix];
      float d = (r == c) ? 1.f : 0.f;
      B4[ix] = (f16)((d - 0.5f*f1 + 0.375f*f2 - 0.3125f*f3) * is2);
    }
  }
  __syncthreads();
  if (t < 128) red[t] = mean[t * 129];
  __syncthreads();
  for (int s = 64; s > 0; s >>= 1) { if (t < s) red[t] += red[t + s]; __syncthreads(); }
  if (t == 0) sv = red[0] / 128.f;
  __syncthreads();
  const float s3 = sv, inv3 = 1.f / s3;
  for (int e = t; e < NN; e += 512) {
    int r = e >> 7, c = e & 127;
    B1[swz(r, c)] = (f16)(mean[e] * inv3 - (r == c ? 1.f : 0.f));
  }
  __syncthreads();
  zero_acc<2>(acc); mm_lds<2>(B1, B1, acc, w, l); wb_t<2>(B2, acc, w, l, 1.f, 0.f); __syncthreads();
  {
    const float rs3 = sqrtf(s3);
    for (int e = t; e < NN; e += 512) {
      int r = e >> 7, c = e & 127; int ix = swz(r, c);
      float m1 = (float)B1[ix], m2 = (float)B2[ix];
      float d = (r == c) ? 1.f : 0.f;
      B3[ix] = (f16)((d + 0.5f*m1 - 0.125f*m2) * rs3);
    }
  }
  __syncthreads();
  zero_acc<2>(acc); mm_lds<2>(B4, B3, acc, w, l);
  {
    const int tr0 = (w >> 1) * 32, tc0 = (w & 1) * 64;
    #pragma unroll
    for (int i = 0; i < 2; ++i) {
      const int rowb = tr0 + i*16 + ((l >> 4) << 2);
      #pragma unroll
      for (int j = 0; j < 4; ++j) {
        const int colg = tc0 + j*16 + (l & 15);
        f16x4 h;
        #pragma unroll
        for (int r = 0; r < 4; ++r) h[r] = (f16)acc[i][j][r];
        *(f16x4*)(Gs + swz(colg, rowb)) = h;
      }
    }
  }
}

// ======== phase E: Xn = G * X * G^T — double-buffered X (hide HBM lat) ======
__global__ __launch_bounds__(256, 1) void k_apply(
    const f16* __restrict__ Xh, const f16* __restrict__ Gs,
    float* __restrict__ Out, int per_blk) {
  __shared__ __align__(16) f16 SX0[NN], SX1[NN];   // 64 KB -> 2 blocks/CU
  const int t = threadIdx.x, w = t >> 6, l = t & 63;
  f16x8 bg[16];
  pre_bf_gswz(Gs, bg, w, l);
  f32x4 acc[4][4];
  stage32_256(Xh + (size_t)blockIdx.x * per_blk * NN, SX0, t);
  for (int m = 0; m < per_blk; ++m) {
    const size_t b = (size_t)blockIdx.x * per_blk + m;
    f16* cur = (m & 1) ? SX1 : SX0;
    f16* nxt = (m & 1) ? SX0 : SX1;
    asm volatile("s_waitcnt vmcnt(0)" ::: "memory");
    __syncthreads();                       // cur's X landed; nxt free
    if (m + 1 < per_blk) stage32_256(Xh + (b + 1) * NN, nxt, t);
    zero_acc<4>(acc); mm_pre<4>(cur, bg, acc, w, l);
    __syncthreads();
    wb_t<4>(cur, acc, w, l, 1.f, 0.f);     // cur := (X*G^T)^T = G*X = T
    __syncthreads();
    zero_acc<4>(acc); mm_pre<4>(cur, bg, acc, w, l);
    float* O = Out + b * NN;
    const int tr0 = (w >> 1) * 64, tc0 = (w & 1) * 64;
    #pragma unroll
    for (int i = 0; i < 4; ++i) {
      const int rowb = tr0 + i*16 + ((l >> 4) << 2);
      #pragma unroll
      for (int j = 0; j < 4; ++j) {
        const int colg = tc0 + j*16 + (l & 15);
        *(f32x4*)(O + colg * 128 + rowb) = acc[i][j];
      }
    }
  }
}

// =================== host ===================
extern "C" void kernel_launch(void* const* d_in, const int* in_sizes, int n_in,
                              void* d_out, int out_size, void* d_ws, size_t ws_size,
                              hipStream_t stream) {
  const float* X    = (const float*)d_in[0];
  const float* mean = (const float*)d_in[1];
  // d_in[2] (running_mean) mathematically unused: eta=1.0 makes
  // rm_sqrt @ powm(rm_invsqrt@BM@rm_invsqrt, 1) @ rm_sqrt == BM for ANY SPD rm.
  const int Bn = in_sizes[0] / NN;       // 2048

  float* wsf = (float*)d_ws;
  float* M0 = wsf;
  float* P  = wsf + NN;
  f16* hbase = (f16*)(wsf + 2 * (size_t)NN);
  f16 *Cps = hbase;                      // swizzled single-f16 Cp
  f16 *Rh  = hbase + NN;                 // row-major single-f16 R
  f16 *Gs  = hbase + 2 * NN;             // swizzled single-f16 G
  float* Ppart = wsf + 4 * (size_t)NN;            // 256 slots (16 MB)
  float* part2 = wsf + (4 + 256) * (size_t)NN;    // 16 slots (1 MB)
  f16* Xh = (f16*)(wsf + (4 + 256 + 16) * (size_t)NN);  // 64 MB pre-swizzled f16 X

  const float invBn = 1.f / (float)Bn;
  k_mean_part<<<dim3(8, 256), 256, 0, stream>>>(X, Xh, Ppart, Bn / 256);
  k_red1<<<dim3(16, 16), 256, 0, stream>>>(Ppart, part2);
  k_red2<<<16, 256, 0, stream>>>(part2, M0, invBn);
  kB<<<1, 512, 0, stream>>>(M0, Cps, Rh);
  k_batch_log<<<256, 512, 0, stream>>>(Xh, Cps, Ppart, Bn / 256);
  k_red1<<<dim3(16, 16), 256, 0, stream>>>(Ppart, part2);
  k_red2<<<16, 256, 0, stream>>>(part2, P, invBn);
  kD<<<1, 512, 0, stream>>>(P, mean, Rh, Gs);
  k_apply<<<512, 256, 0, stream>>>(Xh, Gs, (float*)d_out, Bn / 512);
}